// Round 2
// baseline (386.407 us; speedup 1.0000x reference)
//
#include <hip/hip_runtime.h>
#include <math.h>

// Output: 2 * pe[s][c] broadcast over batch; pe[s][c] = sin(div) if c even else cos(div),
// div = s / 10000^(c/16*2) = s * 2^(-c * log2(10000) / 8).
// Total output: 65536*64*16 = 67,108,864 fp32 = 256 MiB. Pure write, input unused.
//
// R2: same as R1 (nontemporal stores + x8 unroll) with the sizing bug fixed:
// out_size is the FLOAT ELEMENT COUNT (baseline divided by 4 and passed),
// not bytes. R1's /16 wrote only 1/4 of the buffer -> absmax 2.0.

typedef float vfloat4 __attribute__((ext_vector_type(4)));

__global__ __launch_bounds__(256) void pe_broadcast_kernel(vfloat4* __restrict__ out, int total4) {
    const int tid = blockIdx.x * blockDim.x + threadIdx.x;

    // flat float index of this thread's first float4
    const int flat = tid * 4;
    const int s = (flat >> 4) & 63;   // position index 0..63
    const int p = flat & 15;          // channel index of lane's first float (0,4,8,12)

    // Compute the 4 values once; pattern period (1024 floats) divides the grid
    // stride (gridDim*256*4 floats), so each thread's value is loop-invariant.
    const float LOG2_10000_OVER_8 = 1.6609640474436813f; // log2(10000)/8
    vfloat4 v;
#pragma unroll
    for (int k = 0; k < 4; ++k) {
        const int c = p + k;
        const float inv_freq = exp2f(-(float)c * LOG2_10000_OVER_8);
        const float div = (float)s * inv_freq;
        v[k] = 2.0f * (((c & 1) == 0) ? sinf(div) : cosf(div));
    }

    const int stride = gridDim.x * blockDim.x;

    // Main loop unrolled x8: with grid=2048, block=256, total4=16,777,216 each
    // thread does exactly 32 stores -> 4 unrolled iterations, zero tail.
    int i = tid;
    for (; i + 7 * stride < total4; i += 8 * stride) {
#pragma unroll
        for (int k = 0; k < 8; ++k) {
            __builtin_nontemporal_store(v, out + i + k * stride);
        }
    }
    // Tail (not taken at the shipped launch geometry, kept for generality).
    for (; i < total4; i += stride) {
        __builtin_nontemporal_store(v, out + i);
    }
}

extern "C" void kernel_launch(void* const* d_in, const int* in_sizes, int n_in,
                              void* d_out, int out_size, void* d_ws, size_t ws_size,
                              hipStream_t stream) {
    (void)d_in; (void)in_sizes; (void)n_in; (void)d_ws; (void)ws_size;
    vfloat4* out = (vfloat4*)d_out;
    const int total4 = out_size / 4;           // out_size = float count; 16,777,216 float4s
    const int block = 256;
    // 2048 blocks * 256 threads = 524,288 threads = full residency (256 CU * 2048);
    // each thread stores 32 float4s.
    const int grid = 2048;
    pe_broadcast_kernel<<<grid, block, 0, stream>>>(out, total4);
}